// Round 1
// baseline (680.556 us; speedup 1.0000x reference)
//
#include <hip/hip_runtime.h>
#include <math.h>

// Problem constants (from setup_inputs)
#define BB 2      // batch
#define NS 25     // n_way*n_shot support images
#define NQ 16     // queries
#define KW 5      // n_way (classes)
#define C  640
#define HW 25     // H*W, H=W=5
#define C2 1280   // 2*C
#define P  160    // BB*NQ*KW pairs

// Workspace layout (float offsets)
#define WS_PROTO   0          // BB*KW*C*HW           = 160000
#define WS_OFF     160000     // P*18*HW              =  72000
#define WS_FILT    232000     // P*9*HW               =  36000
#define WS_WT      268000     // C2*25*20 (o pad 20)  = 640000
#define WS_WDT     908000     // 9*C*9                =  51840
#define WS_NORM    959840     // BB*KW*HW             =    250
#define WS_CW      960090     // BB*KW*C              =   6400
#define WS_PART    966490     // P*5                  =    800

// ---------------- proto: class prototypes -------------------------------
__global__ void k_proto(const float* __restrict__ sf, const float* __restrict__ st,
                        float* __restrict__ proto) {
    int idx = blockIdx.x * 256 + threadIdx.x;
    if (idx >= BB * KW * C * HW) return;
    int hw = idx % HW; int r = idx / HW;
    int c = r % C; r /= C;
    int k = r % KW; int bi = r / KW;
    float num = 0.f, den = 0.f;
    for (int n = 0; n < NS; ++n) {
        float w = st[(bi * NS + n) * KW + k];
        num += w * sf[((bi * NS + n) * C + c) * HW + hw];
        den += w;
    }
    proto[idx] = num / den;
}

// ---------------- per-(b,k,hw) channel norms ----------------------------
__global__ void k_norm(const float* __restrict__ proto, float* __restrict__ norms) {
    int i = threadIdx.x;
    if (i >= BB * KW * HW) return;
    int hw = i % HW; int r = i / HW;
    int k = r % KW; int bi = r / KW;
    const float* pr = proto + ((bi * KW + k) * C) * HW + hw;
    float s = 0.f;
    for (int c = 0; c < C; ++c) { float v = pr[c * HW]; s += v * v; }
    norms[i] = fmaxf(sqrtf(s), 1e-12f);
}

// ---------------- cw2[b,k,c] = mean_hw proto/norm -----------------------
__global__ void k_cw(const float* __restrict__ proto, const float* __restrict__ norms,
                     float* __restrict__ cw) {
    int idx = blockIdx.x * 256 + threadIdx.x;
    if (idx >= BB * KW * C) return;
    int c = idx % C; int r = idx / C;
    int k = r % KW; int bi = r / KW;
    const float* pr = proto + ((bi * KW + k) * C + c) * HW;
    const float* nm = norms + (bi * KW + k) * HW;
    float s = 0.f;
    #pragma unroll
    for (int hw = 0; hw < HW; ++hw) s += pr[hw] / nm[hw];
    cw[idx] = s * (1.f / 25.f);
}

// ---------------- transpose w_off -> wT[(c*25+t)*20 + o] ----------------
__global__ void k_wt(const float* __restrict__ w_off, float* __restrict__ wT) {
    int idx = blockIdx.x * 256 + threadIdx.x;
    if (idx >= C2 * 25 * 20) return;
    int o = idx % 20; int r = idx / 20;
    int t = r % 25; int c = r / 25;
    wT[idx] = (o < 18) ? w_off[(o * C2 + c) * 25 + t] : 0.f;
}

// ---------------- transpose w_def -> wdT[(k*C+c)*9 + o] -----------------
__global__ void k_wd(const float* __restrict__ w_def, float* __restrict__ wdT) {
    int idx = blockIdx.x * 256 + threadIdx.x;
    if (idx >= 9 * C * 9) return;
    int o = idx % 9; int r = idx / 9;
    int c = r % C; int kk = r / C;
    wdT[idx] = w_def[(o * C + c) * 9 + kk];
}

// ---------------- 5x5 offset conv (pad 2) -------------------------------
// block = one pair p. 240 active threads: kslice(16) x [sy(5) x ogrp(3)].
// LDS: padded input chunk [160 ch][81 pos]; reused for K-slice reduction.
__launch_bounds__(256)
__global__ void k_off(const float* __restrict__ qf, const float* __restrict__ proto,
                      const float* __restrict__ wT, float* __restrict__ offo) {
    __shared__ float lds[12960];
    int p = blockIdx.x;
    int bi = p / (NQ * KW); int rem = p % (NQ * KW);
    int q = rem / KW; int k = rem % KW;
    const float* fte = qf + ((bi * NQ + q) * C) * HW;
    const float* ftr = proto + ((bi * KW + k) * C) * HW;
    int tid = threadIdx.x;

    float acc[5][6];
    #pragma unroll
    for (int i = 0; i < 5; ++i)
        #pragma unroll
        for (int j = 0; j < 6; ++j) acc[i][j] = 0.f;

    int kslice = tid / 15, tile = tid % 15;
    int sy = tile / 3, og = (tile % 3) * 6;

    for (int ch = 0; ch < 8; ++ch) {
        int cbase = ch * 160;
        __syncthreads();
        for (int i = tid; i < 160 * 81; i += 256) {
            int cc = i / 81, pos = i % 81;
            int y = pos / 9 - 2, x = pos % 9 - 2;
            int cg = cbase + cc;
            float v = 0.f;
            if (y >= 0 && y < 5 && x >= 0 && x < 5)
                v = (cg < C) ? fte[cg * HW + y * 5 + x] : ftr[(cg - C) * HW + y * 5 + x];
            lds[i] = v;
        }
        __syncthreads();
        if (tid < 240) {
            for (int cp = 0; cp < 10; ++cp) {
                int cc = kslice * 10 + cp;
                const float* irow = &lds[cc * 81 + sy * 9];
                const float* wrow = wT + ((cbase + cc) * 25) * 20 + og;
                #pragma unroll
                for (int t = 0; t < 25; ++t) {
                    const int ky = t / 5, kx = t % 5;
                    const float* ip = irow + ky * 9 + kx;
                    const float* wp = wrow + t * 20;
                    float a[5], wv[6];
                    #pragma unroll
                    for (int i2 = 0; i2 < 5; ++i2) a[i2] = ip[i2];
                    #pragma unroll
                    for (int j2 = 0; j2 < 6; ++j2) wv[j2] = wp[j2];
                    #pragma unroll
                    for (int i2 = 0; i2 < 5; ++i2)
                        #pragma unroll
                        for (int j2 = 0; j2 < 6; ++j2)
                            acc[i2][j2] = fmaf(a[i2], wv[j2], acc[i2][j2]);
                }
            }
        }
    }
    __syncthreads();
    if (tid < 240) {
        #pragma unroll
        for (int i = 0; i < 5; ++i)
            #pragma unroll
            for (int j = 0; j < 6; ++j)
                lds[(tile * 30 + i * 6 + j) * 16 + kslice] = acc[i][j];
    }
    __syncthreads();
    for (int oi = tid; oi < 450; oi += 256) {
        int tl = oi / 30, r2 = oi % 30, i = r2 / 6, j = r2 % 6;
        float s = 0.f;
        #pragma unroll
        for (int ks = 0; ks < 16; ++ks) s += lds[oi * 16 + ks];
        int o = (tl % 3) * 6 + j;
        int sy2 = tl / 3;
        offo[p * 450 + o * 25 + sy2 * 5 + i] = s;
    }
}

// ---------------- deformable 3x3 conv + sigmoid -> filt -----------------
// block = one pair p; thread (hw,kk) for tid<225. ftr staged in LDS.
__launch_bounds__(256)
__global__ void k_def(const float* __restrict__ proto, const float* __restrict__ offo,
                      const float* __restrict__ wdT, float* __restrict__ filt) {
    __shared__ float lds[16000];
    int p = blockIdx.x;
    int bi = p / (NQ * KW); int rem = p % (NQ * KW);
    int k = rem % KW;
    const float* ftr = proto + ((bi * KW + k) * C) * HW;
    int tid = threadIdx.x;
    for (int i = tid; i < C * HW; i += 256) lds[i] = ftr[i];
    __syncthreads();

    float acc[9];
    bool act = tid < 225;
    int hw = tid / 9, kk = tid % 9;
    int idx0 = 0, idx1 = 0, idx2 = 0, idx3 = 0;
    float wb0 = 0.f, wb1 = 0.f, wb2 = 0.f, wb3 = 0.f;
    if (act) {
        int h = hw / 5, w = hw % 5, ky = kk / 3, kx = kk % 3;
        float offY = offo[p * 450 + (kk * 2 + 0) * 25 + hw];
        float offX = offo[p * 450 + (kk * 2 + 1) * 25 + hw];
        float py = (float)(h + ky - 1) + offY;
        float px = (float)(w + kx - 1) + offX;
        float y0f = floorf(py), x0f = floorf(px);
        float ty = py - y0f, tx = px - x0f;
        int y0 = (int)y0f, x0 = (int)x0f;
        int y1 = y0 + 1, x1 = x0 + 1;
        bool vy0 = (y0 >= 0 && y0 < 5), vy1 = (y1 >= 0 && y1 < 5);
        bool vx0 = (x0 >= 0 && x0 < 5), vx1 = (x1 >= 0 && x1 < 5);
        int cy0 = min(max(y0, 0), 4), cy1 = min(max(y1, 0), 4);
        int cx0 = min(max(x0, 0), 4), cx1 = min(max(x1, 0), 4);
        idx0 = cy0 * 5 + cx0; idx1 = cy0 * 5 + cx1;
        idx2 = cy1 * 5 + cx0; idx3 = cy1 * 5 + cx1;
        wb0 = (vy0 && vx0) ? (1.f - ty) * (1.f - tx) : 0.f;
        wb1 = (vy0 && vx1) ? (1.f - ty) * tx : 0.f;
        wb2 = (vy1 && vx0) ? ty * (1.f - tx) : 0.f;
        wb3 = (vy1 && vx1) ? ty * tx : 0.f;
        #pragma unroll
        for (int o = 0; o < 9; ++o) acc[o] = 0.f;
        for (int c = 0; c < C; ++c) {
            const float* base = &lds[c * HW];
            float s = wb0 * base[idx0] + wb1 * base[idx1] + wb2 * base[idx2] + wb3 * base[idx3];
            const float* wr = wdT + (kk * C + c) * 9;
            #pragma unroll
            for (int o = 0; o < 9; ++o) acc[o] = fmaf(s, wr[o], acc[o]);
        }
    }
    __syncthreads();
    if (act) {
        #pragma unroll
        for (int o = 0; o < 9; ++o) lds[tid * 9 + o] = acc[o];
    }
    __syncthreads();
    if (tid < 225) {
        int hw2 = tid / 9, o2 = tid % 9;
        float s = 0.f;
        #pragma unroll
        for (int kk2 = 0; kk2 < 9; ++kk2) s += lds[(hw2 * 9 + kk2) * 9 + o2];
        filt[p * 225 + o2 * 25 + hw2] = 1.f / (1.f + expf(-s));
    }
}

// ---------------- RK4 dynamic depthwise filter + class score ------------
// g(): out[hw] = relu(sum_k q_pad[h+dy-1,w+dx-1] * fl[hw*9+k])  (depthwise)
#define GSTEP(QA, KA)                                                       \
    {                                                                       \
        _Pragma("unroll")                                                   \
        for (int hw_ = 0; hw_ < 25; ++hw_) {                                \
            const int h_ = hw_ / 5, w_ = hw_ % 5;                           \
            float s_ = 0.f;                                                 \
            _Pragma("unroll")                                               \
            for (int kp_ = 0; kp_ < 9; ++kp_) {                             \
                const int y_ = h_ + kp_ / 3 - 1, x_ = w_ + kp_ % 3 - 1;     \
                if (y_ >= 0 && y_ < 5 && x_ >= 0 && x_ < 5)                 \
                    s_ = fmaf(QA[y_ * 5 + x_], fl[hw_ * 9 + kp_], s_);      \
            }                                                               \
            KA[hw_] = fmaxf(s_, 0.f);                                       \
        }                                                                   \
    }

__launch_bounds__(128)
__global__ void k_rk(const float* __restrict__ qf, const float* __restrict__ filt,
                     const float* __restrict__ cw, float* __restrict__ part) {
    __shared__ float fl[225];
    __shared__ float wsum[2];
    int bid = blockIdx.x;
    int p = bid / 5, ch = bid % 5;
    int bi = p / (NQ * KW); int rem = p % (NQ * KW);
    int q = rem / KW; int k = rem % KW;
    int tid = threadIdx.x;
    int c = ch * 128 + tid;
    for (int i = tid; i < 225; i += 128) fl[i] = filt[p * 225 + i];
    __syncthreads();

    float F[25], K1[25], K2[25], K3[25], Q[25];
    const float* fp = qf + ((bi * NQ + q) * C + c) * HW;
    #pragma unroll
    for (int i = 0; i < 25; ++i) F[i] = fp[i];

    GSTEP(F, K1);                                   // k1
    #pragma unroll
    for (int i = 0; i < 25; ++i) Q[i] = F[i] + K1[i] * (1.f / 3.f);
    GSTEP(Q, K2);                                   // k2
    #pragma unroll
    for (int i = 0; i < 25; ++i) Q[i] = F[i] + K2[i] - K1[i] * (1.f / 3.f);
    GSTEP(Q, K3);                                   // k3
    #pragma unroll
    for (int i = 0; i < 25; ++i) {
        Q[i] = F[i] + K1[i] - K2[i] + K3[i];
        K1[i] += 3.f * (K2[i] + K3[i]);             // acc = k1+3k2+3k3
    }
    GSTEP(Q, K3);                                   // k4 into K3

    float S = 0.f;
    #pragma unroll
    for (int i = 0; i < 25; ++i) S += F[i] + (K1[i] + K3[i]) * 0.125f;

    float val = cw[(bi * KW + k) * C + c] * S;
    #pragma unroll
    for (int off = 32; off > 0; off >>= 1) val += __shfl_down(val, off, 64);
    if ((tid & 63) == 0) wsum[tid >> 6] = val;
    __syncthreads();
    if (tid == 0) part[p * 5 + ch] = wsum[0] + wsum[1];
}

// ---------------- final: sum partials, /49 ------------------------------
__global__ void k_fin(const float* __restrict__ part, float* __restrict__ out) {
    int i = blockIdx.x * 256 + threadIdx.x;
    if (i < P) {
        float s = 0.f;
        #pragma unroll
        for (int ch = 0; ch < 5; ++ch) s += part[i * 5 + ch];
        out[i] = s * (1.f / 49.f);
    }
}

extern "C" void kernel_launch(void* const* d_in, const int* in_sizes, int n_in,
                              void* d_out, int out_size, void* d_ws, size_t ws_size,
                              hipStream_t stream) {
    const float* sf    = (const float*)d_in[0];   // support_feat
    const float* qf    = (const float*)d_in[1];   // query_feat
    const float* st    = (const float*)d_in[2];   // support_targets
    const float* w_off = (const float*)d_in[4];   // w_off
    const float* w_def = (const float*)d_in[5];   // w_def
    float* out = (float*)d_out;
    float* ws  = (float*)d_ws;

    k_proto<<<(BB * KW * C * HW + 255) / 256, 256, 0, stream>>>(sf, st, ws + WS_PROTO);
    k_wt<<<(C2 * 25 * 20 + 255) / 256, 256, 0, stream>>>(w_off, ws + WS_WT);
    k_wd<<<(9 * C * 9 + 255) / 256, 256, 0, stream>>>(w_def, ws + WS_WDT);
    k_norm<<<1, 256, 0, stream>>>(ws + WS_PROTO, ws + WS_NORM);
    k_cw<<<(BB * KW * C + 255) / 256, 256, 0, stream>>>(ws + WS_PROTO, ws + WS_NORM, ws + WS_CW);
    k_off<<<P, 256, 0, stream>>>(qf, ws + WS_PROTO, ws + WS_WT, ws + WS_OFF);
    k_def<<<P, 256, 0, stream>>>(ws + WS_PROTO, ws + WS_OFF, ws + WS_WDT, ws + WS_FILT);
    k_rk<<<P * 5, 128, 0, stream>>>(qf, ws + WS_FILT, ws + WS_CW, ws + WS_PART);
    k_fin<<<1, 256, 0, stream>>>(ws + WS_PART, out);
}

// Round 2
// 222.378 us; speedup vs baseline: 3.0604x; 3.0604x over previous
//
#include <hip/hip_runtime.h>
#include <math.h>

// Problem constants
#define BB 2      // batch
#define NS 25     // support images
#define NQ 16     // queries
#define KW 5      // n_way
#define C  640
#define HW 25     // 5x5
#define C2 1280
#define P  160    // BB*NQ*KW

// Workspace layout (float offsets)
#define WS_PROTO   0          // 160000
#define WS_OFF     160000     // 72000
#define WS_FILT    232000     // 36000
#define WS_WDT     268000     // 51840
#define WS_NORM    319840     // 250
#define WS_CW      320090     // 6400
#define WS_PART    326490     // 800
#define WS_WT      327290     // C2*25*24 = 768000
#define WS_FILTP   327290     // alias WT (dead by k_def) P*8*225 = 288000
#define WS_OFFP    1095290    // P*8*450 = 576000 -> 1671290 floats (6.7MB)

// ---------------- proto -------------------------------------------------
__global__ void k_proto(const float* __restrict__ sf, const float* __restrict__ st,
                        float* __restrict__ proto) {
    int idx = blockIdx.x * 256 + threadIdx.x;
    if (idx >= BB * KW * C * HW) return;
    int hw = idx % HW; int r = idx / HW;
    int c = r % C; r /= C;
    int k = r % KW; int bi = r / KW;
    float num = 0.f, den = 0.f;
    for (int n = 0; n < NS; ++n) {
        float w = st[(bi * NS + n) * KW + k];
        num += w * sf[((bi * NS + n) * C + c) * HW + hw];
        den += w;
    }
    proto[idx] = num / den;
}

// ---------------- norms -------------------------------------------------
__global__ void k_norm(const float* __restrict__ proto, float* __restrict__ norms) {
    int i = threadIdx.x;
    if (i >= BB * KW * HW) return;
    int hw = i % HW; int r = i / HW;
    int k = r % KW; int bi = r / KW;
    const float* pr = proto + ((bi * KW + k) * C) * HW + hw;
    float s = 0.f;
    for (int c = 0; c < C; ++c) { float v = pr[c * HW]; s += v * v; }
    norms[i] = fmaxf(sqrtf(s), 1e-12f);
}

// ---------------- cw ----------------------------------------------------
__global__ void k_cw(const float* __restrict__ proto, const float* __restrict__ norms,
                     float* __restrict__ cw) {
    int idx = blockIdx.x * 256 + threadIdx.x;
    if (idx >= BB * KW * C) return;
    int c = idx % C; int r = idx / C;
    int k = r % KW; int bi = r / KW;
    const float* pr = proto + ((bi * KW + k) * C + c) * HW;
    const float* nm = norms + (bi * KW + k) * HW;
    float s = 0.f;
    #pragma unroll
    for (int hw = 0; hw < HW; ++hw) s += pr[hw] / nm[hw];
    cw[idx] = s * (1.f / 25.f);
}

// ---------------- w_off repack: [(c*25+t)*24 + g*8 + j], o = g*6+j ------
__global__ void k_wt(const float* __restrict__ w_off, float* __restrict__ wT) {
    int idx = blockIdx.x * 256 + threadIdx.x;
    if (idx >= C2 * 25 * 24) return;
    int o24 = idx % 24; int r = idx / 24;
    int t = r % 25; int c = r / 25;
    int g = o24 / 8, j = o24 % 8;
    int o = g * 6 + j;
    wT[idx] = (j < 6 && o < 18) ? w_off[(o * C2 + c) * 25 + t] : 0.f;
}

// ---------------- w_def transpose: wdT[(kk*C+c)*9 + o] ------------------
__global__ void k_wd(const float* __restrict__ w_def, float* __restrict__ wdT) {
    int idx = blockIdx.x * 256 + threadIdx.x;
    if (idx >= 9 * C * 9) return;
    int o = idx % 9; int r = idx / 9;
    int c = r % C; int kk = r / C;
    wdT[idx] = w_def[(o * C + c) * 9 + kk];
}

// ---------------- 5x5 offset conv, K-split 8 ----------------------------
// grid (P, 8). Each block: one 160-channel chunk of the 1280-deep K.
// 240 active threads: kslice(16) x [sy(5) x ogrp(3)]; acc[5 x][6 o].
__launch_bounds__(256)
__global__ void k_off(const float* __restrict__ qf, const float* __restrict__ proto,
                      const float* __restrict__ wT, float* __restrict__ offp) {
    __shared__ float lds[12960];     // [160 ch][81 padded pos]
    int p = blockIdx.x;
    int kchunk = blockIdx.y;
    int cbase = kchunk * 160;
    int bi = p / (NQ * KW); int rem = p % (NQ * KW);
    int q = rem / KW; int k = rem % KW;
    const float* src = (cbase < C)
        ? qf + ((bi * NQ + q) * C + cbase) * HW
        : proto + ((bi * KW + k) * C + (cbase - C)) * HW;
    int tid = threadIdx.x;

    for (int i = tid; i < 12960; i += 256) lds[i] = 0.f;
    __syncthreads();
    for (int i = tid; i < 160 * 25; i += 256) {
        int cc = i / 25, pos = i % 25;
        lds[cc * 81 + (pos / 5 + 2) * 9 + (pos % 5 + 2)] = src[i];
    }
    __syncthreads();

    int kslice = tid / 15, tile = tid % 15;
    int sy = tile / 3, og = (tile % 3) * 8;
    float acc[5][6];
    #pragma unroll
    for (int i = 0; i < 5; ++i)
        #pragma unroll
        for (int j = 0; j < 6; ++j) acc[i][j] = 0.f;

    if (tid < 240) {
        const float* wbase = wT + (size_t)cbase * 25 * 24 + og;
        for (int cp = 0; cp < 10; ++cp) {
            int cc = kslice * 10 + cp;
            const float* irow = &lds[cc * 81 + sy * 9];
            const float* wrow = wbase + (size_t)cc * 25 * 24;
            #pragma unroll
            for (int t = 0; t < 25; ++t) {
                const int ky = t / 5, kx = t % 5;
                const float* ip = irow + ky * 9 + kx;
                const float* wp = wrow + t * 24;
                float a[5], wv[6];
                #pragma unroll
                for (int i2 = 0; i2 < 5; ++i2) a[i2] = ip[i2];
                #pragma unroll
                for (int j2 = 0; j2 < 6; ++j2) wv[j2] = wp[j2];
                #pragma unroll
                for (int i2 = 0; i2 < 5; ++i2)
                    #pragma unroll
                    for (int j2 = 0; j2 < 6; ++j2)
                        acc[i2][j2] = fmaf(a[i2], wv[j2], acc[i2][j2]);
            }
        }
    }
    __syncthreads();
    if (tid < 240) {
        #pragma unroll
        for (int i = 0; i < 5; ++i)
            #pragma unroll
            for (int j = 0; j < 6; ++j)
                lds[(tile * 30 + i * 6 + j) * 16 + kslice] = acc[i][j];
    }
    __syncthreads();
    float* dst = offp + ((size_t)p * 8 + kchunk) * 450;
    for (int oi = tid; oi < 450; oi += 256) {
        int tl = oi / 30, r2 = oi % 30, i = r2 / 6, j = r2 % 6;
        float s = 0.f;
        #pragma unroll
        for (int ks = 0; ks < 16; ++ks) s += lds[oi * 16 + ks];
        int o = (tl % 3) * 6 + j;
        dst[o * 25 + (tl / 3) * 5 + i] = s;
    }
}

// ---------------- reduce k_off partials ---------------------------------
__global__ void k_offred(const float* __restrict__ offp, float* __restrict__ offo) {
    int idx = blockIdx.x * 256 + threadIdx.x;
    if (idx >= P * 450) return;
    int p = idx / 450, e = idx % 450;
    float s = 0.f;
    #pragma unroll
    for (int kc = 0; kc < 8; ++kc) s += offp[((size_t)p * 8 + kc) * 450 + e];
    offo[idx] = s;
}

// ---------------- deformable 3x3 conv, C-split 8 ------------------------
// grid (P, 8): 80 channels each. thread (hw,kk) for tid<225.
__launch_bounds__(256)
__global__ void k_def(const float* __restrict__ proto, const float* __restrict__ offo,
                      const float* __restrict__ wdT, float* __restrict__ filtp) {
    __shared__ float flds[2000];     // [80 ch][25]
    __shared__ float wlds[8640];     // [(cc*9+kk)*12 + o]
    int p = blockIdx.x;
    int cs = blockIdx.y;
    int cbase = cs * 80;
    int bi = p / (NQ * KW); int rem = p % (NQ * KW);
    int k = rem % KW;
    const float* ftr = proto + ((bi * KW + k) * C + cbase) * HW;
    int tid = threadIdx.x;
    for (int i = tid; i < 2000; i += 256) flds[i] = ftr[i];
    for (int i = tid; i < 9 * 720; i += 256) {
        int kk = i / 720, r = i % 720;
        int cc = r / 9, o = r % 9;
        wlds[(cc * 9 + kk) * 12 + o] = wdT[(kk * C + cbase + cc) * 9 + o];
    }
    __syncthreads();

    float acc[9];
    #pragma unroll
    for (int o = 0; o < 9; ++o) acc[o] = 0.f;
    bool act = tid < 225;
    int hw = tid / 9, kk = tid % 9;
    if (act) {
        int h = hw / 5, w = hw % 5, ky = kk / 3, kx = kk % 3;
        float offY = offo[p * 450 + (kk * 2 + 0) * 25 + hw];
        float offX = offo[p * 450 + (kk * 2 + 1) * 25 + hw];
        float py = (float)(h + ky - 1) + offY;
        float px = (float)(w + kx - 1) + offX;
        float y0f = floorf(py), x0f = floorf(px);
        float ty = py - y0f, tx = px - x0f;
        int y0 = (int)y0f, x0 = (int)x0f;
        int y1 = y0 + 1, x1 = x0 + 1;
        bool vy0 = (y0 >= 0 && y0 < 5), vy1 = (y1 >= 0 && y1 < 5);
        bool vx0 = (x0 >= 0 && x0 < 5), vx1 = (x1 >= 0 && x1 < 5);
        int cy0 = min(max(y0, 0), 4), cy1 = min(max(y1, 0), 4);
        int cx0 = min(max(x0, 0), 4), cx1 = min(max(x1, 0), 4);
        int idx0 = cy0 * 5 + cx0, idx1 = cy0 * 5 + cx1;
        int idx2 = cy1 * 5 + cx0, idx3 = cy1 * 5 + cx1;
        float wb0 = (vy0 && vx0) ? (1.f - ty) * (1.f - tx) : 0.f;
        float wb1 = (vy0 && vx1) ? (1.f - ty) * tx : 0.f;
        float wb2 = (vy1 && vx0) ? ty * (1.f - tx) : 0.f;
        float wb3 = (vy1 && vx1) ? ty * tx : 0.f;
        for (int cc = 0; cc < 80; ++cc) {
            const float* base = &flds[cc * 25];
            float s = wb0 * base[idx0] + wb1 * base[idx1] + wb2 * base[idx2] + wb3 * base[idx3];
            const float* wr = &wlds[(cc * 9 + kk) * 12];
            #pragma unroll
            for (int o = 0; o < 9; ++o) acc[o] = fmaf(s, wr[o], acc[o]);
        }
    }
    __syncthreads();
    // reuse flds+wlds region as scratch [225][9]
    if (act) {
        #pragma unroll
        for (int o = 0; o < 9; ++o) flds[tid * 9 + o] = acc[o];
    }
    __syncthreads();
    if (tid < 225) {
        int hw2 = tid / 9, o2 = tid % 9;
        float s = 0.f;
        #pragma unroll
        for (int kk2 = 0; kk2 < 9; ++kk2) s += flds[(hw2 * 9 + kk2) * 9 + o2];
        filtp[((size_t)p * 8 + cs) * 225 + o2 * 25 + hw2] = s;
    }
}

// ---------------- reduce k_def partials + sigmoid -----------------------
__global__ void k_defred(const float* __restrict__ filtp, float* __restrict__ filt) {
    int idx = blockIdx.x * 256 + threadIdx.x;
    if (idx >= P * 225) return;
    int p = idx / 225, e = idx % 225;
    float s = 0.f;
    #pragma unroll
    for (int cs = 0; cs < 8; ++cs) s += filtp[((size_t)p * 8 + cs) * 225 + e];
    filt[idx] = 1.f / (1.f + expf(-s));
}

// ---------------- RK4 dynamic depthwise + class score -------------------
#define GSTEP(QA, KA)                                                       \
    {                                                                       \
        _Pragma("unroll")                                                   \
        for (int hw_ = 0; hw_ < 25; ++hw_) {                                \
            const int h_ = hw_ / 5, w_ = hw_ % 5;                           \
            float s_ = 0.f;                                                 \
            _Pragma("unroll")                                               \
            for (int kp_ = 0; kp_ < 9; ++kp_) {                             \
                const int y_ = h_ + kp_ / 3 - 1, x_ = w_ + kp_ % 3 - 1;     \
                if (y_ >= 0 && y_ < 5 && x_ >= 0 && x_ < 5)                 \
                    s_ = fmaf(QA[y_ * 5 + x_], fl[hw_ * 9 + kp_], s_);      \
            }                                                               \
            KA[hw_] = fmaxf(s_, 0.f);                                       \
        }                                                                   \
    }

__launch_bounds__(128)
__global__ void k_rk(const float* __restrict__ qf, const float* __restrict__ filt,
                     const float* __restrict__ cw, float* __restrict__ part) {
    __shared__ float fl[225];
    __shared__ float qlds[3200];     // 128 ch x 25
    __shared__ float wsum[2];
    int bid = blockIdx.x;
    int p = bid / 5, ch = bid % 5;
    int bi = p / (NQ * KW); int rem = p % (NQ * KW);
    int q = rem / KW; int k = rem % KW;
    int tid = threadIdx.x;
    int c = ch * 128 + tid;
    for (int i = tid; i < 225; i += 128) fl[i] = filt[p * 225 + i];
    const float* qbase = qf + ((bi * NQ + q) * C + ch * 128) * HW;
    for (int i = tid; i < 3200; i += 128) qlds[i] = qbase[i];
    __syncthreads();

    float F[25], K1[25], K2[25], K3[25], Q[25];
    #pragma unroll
    for (int i = 0; i < 25; ++i) F[i] = qlds[tid * 25 + i];

    GSTEP(F, K1);
    #pragma unroll
    for (int i = 0; i < 25; ++i) Q[i] = F[i] + K1[i] * (1.f / 3.f);
    GSTEP(Q, K2);
    #pragma unroll
    for (int i = 0; i < 25; ++i) Q[i] = F[i] + K2[i] - K1[i] * (1.f / 3.f);
    GSTEP(Q, K3);
    #pragma unroll
    for (int i = 0; i < 25; ++i) {
        Q[i] = F[i] + K1[i] - K2[i] + K3[i];
        K1[i] += 3.f * (K2[i] + K3[i]);
    }
    GSTEP(Q, K3);

    float S = 0.f;
    #pragma unroll
    for (int i = 0; i < 25; ++i) S += F[i] + (K1[i] + K3[i]) * 0.125f;

    float val = cw[(bi * KW + k) * C + c] * S;
    #pragma unroll
    for (int off = 32; off > 0; off >>= 1) val += __shfl_down(val, off, 64);
    if ((tid & 63) == 0) wsum[tid >> 6] = val;
    __syncthreads();
    if (tid == 0) part[p * 5 + ch] = wsum[0] + wsum[1];
}

// ---------------- final -------------------------------------------------
__global__ void k_fin(const float* __restrict__ part, float* __restrict__ out) {
    int i = blockIdx.x * 256 + threadIdx.x;
    if (i < P) {
        float s = 0.f;
        #pragma unroll
        for (int ch = 0; ch < 5; ++ch) s += part[i * 5 + ch];
        out[i] = s * (1.f / 49.f);
    }
}

extern "C" void kernel_launch(void* const* d_in, const int* in_sizes, int n_in,
                              void* d_out, int out_size, void* d_ws, size_t ws_size,
                              hipStream_t stream) {
    const float* sf    = (const float*)d_in[0];
    const float* qf    = (const float*)d_in[1];
    const float* st    = (const float*)d_in[2];
    const float* w_off = (const float*)d_in[4];
    const float* w_def = (const float*)d_in[5];
    float* out = (float*)d_out;
    float* ws  = (float*)d_ws;

    k_proto<<<(BB * KW * C * HW + 255) / 256, 256, 0, stream>>>(sf, st, ws + WS_PROTO);
    k_wt<<<(C2 * 25 * 24 + 255) / 256, 256, 0, stream>>>(w_off, ws + WS_WT);
    k_wd<<<(9 * C * 9 + 255) / 256, 256, 0, stream>>>(w_def, ws + WS_WDT);
    k_norm<<<1, 256, 0, stream>>>(ws + WS_PROTO, ws + WS_NORM);
    k_cw<<<(BB * KW * C + 255) / 256, 256, 0, stream>>>(ws + WS_PROTO, ws + WS_NORM, ws + WS_CW);
    k_off<<<dim3(P, 8), 256, 0, stream>>>(qf, ws + WS_PROTO, ws + WS_WT, ws + WS_OFFP);
    k_offred<<<(P * 450 + 255) / 256, 256, 0, stream>>>(ws + WS_OFFP, ws + WS_OFF);
    k_def<<<dim3(P, 8), 256, 0, stream>>>(ws + WS_PROTO, ws + WS_OFF, ws + WS_WDT, ws + WS_FILTP);
    k_defred<<<(P * 225 + 255) / 256, 256, 0, stream>>>(ws + WS_FILTP, ws + WS_FILT);
    k_rk<<<P * 5, 128, 0, stream>>>(qf, ws + WS_FILT, ws + WS_CW, ws + WS_PART);
    k_fin<<<1, 256, 0, stream>>>(ws + WS_PART, out);
}

// Round 3
// 162.229 us; speedup vs baseline: 4.1950x; 1.3708x over previous
//
#include <hip/hip_runtime.h>
#include <math.h>

// Problem constants
#define BB 2      // batch
#define NS 25     // support images
#define NQ 16     // queries
#define KW 5      // n_way
#define C  640
#define HW 25     // 5x5
#define C2 1280
#define P  160    // BB*NQ*KW

// Workspace layout (float offsets)
#define WS_PROTO   0          // 160000
#define WS_OFF     160000     // 72000
#define WS_FILT    232000     // 36000
#define WS_WDT     268000     // 51840
#define WS_NORM    319840     // 250
#define WS_CW      320090     // 6400
#define WS_PART    326490     // 800
#define WS_WT      327290     // C2*25*24 = 768000
#define WS_FILTP   327290     // alias WT (dead by k_def) P*8*225 = 288000
#define WS_OFFP    1095290    // P*16*450 = 1152000 -> ends 2247290 (9.0MB)

// ---------------- proto -------------------------------------------------
__global__ void k_proto(const float* __restrict__ sf, const float* __restrict__ st,
                        float* __restrict__ proto) {
    int idx = blockIdx.x * 256 + threadIdx.x;
    if (idx >= BB * KW * C * HW) return;
    int hw = idx % HW; int r = idx / HW;
    int c = r % C; r /= C;
    int k = r % KW; int bi = r / KW;
    float num = 0.f, den = 0.f;
    for (int n = 0; n < NS; ++n) {
        float w = st[(bi * NS + n) * KW + k];
        num += w * sf[((bi * NS + n) * C + c) * HW + hw];
        den += w;
    }
    proto[idx] = num / den;
}

// ---------------- norms -------------------------------------------------
__global__ void k_norm(const float* __restrict__ proto, float* __restrict__ norms) {
    int i = threadIdx.x;
    if (i >= BB * KW * HW) return;
    int hw = i % HW; int r = i / HW;
    int k = r % KW; int bi = r / KW;
    const float* pr = proto + ((bi * KW + k) * C) * HW + hw;
    float s = 0.f;
    for (int c = 0; c < C; ++c) { float v = pr[c * HW]; s += v * v; }
    norms[i] = fmaxf(sqrtf(s), 1e-12f);
}

// ---------------- cw ----------------------------------------------------
__global__ void k_cw(const float* __restrict__ proto, const float* __restrict__ norms,
                     float* __restrict__ cw) {
    int idx = blockIdx.x * 256 + threadIdx.x;
    if (idx >= BB * KW * C) return;
    int c = idx % C; int r = idx / C;
    int k = r % KW; int bi = r / KW;
    const float* pr = proto + ((bi * KW + k) * C + c) * HW;
    const float* nm = norms + (bi * KW + k) * HW;
    float s = 0.f;
    #pragma unroll
    for (int hw = 0; hw < HW; ++hw) s += pr[hw] / nm[hw];
    cw[idx] = s * (1.f / 25.f);
}

// ---------------- w_off repack: [(c*25+t)*24 + g*8 + j], o = g*6+j ------
__global__ void k_wt(const float* __restrict__ w_off, float* __restrict__ wT) {
    int idx = blockIdx.x * 256 + threadIdx.x;
    if (idx >= C2 * 25 * 24) return;
    int o24 = idx % 24; int r = idx / 24;
    int t = r % 25; int c = r / 25;
    int g = o24 / 8, j = o24 % 8;
    int o = g * 6 + j;
    wT[idx] = (j < 6 && o < 18) ? w_off[(o * C2 + c) * 25 + t] : 0.f;
}

// ---------------- w_def transpose: wdT[(kk*C+c)*9 + o] ------------------
__global__ void k_wd(const float* __restrict__ w_def, float* __restrict__ wdT) {
    int idx = blockIdx.x * 256 + threadIdx.x;
    if (idx >= 9 * C * 9) return;
    int o = idx % 9; int r = idx / 9;
    int c = r % C; int kk = r / C;
    wdT[idx] = w_def[(o * C + c) * 9 + kk];
}

// ---------------- 5x5 offset conv, K-split 16 ---------------------------
// grid (P, 16). Each block: 80 channels. 240 active threads:
// kslice(16, 5 ch each) x [sy(5) x ogrp(3)]; acc[5 x][6 o].
// LDS input: [80 ch][9 rows x 12 (pad)]  ch stride 108 dwords (16B-aligned).
// Inner loop: whole padded row -> registers (float4 x2 + float), 25 taps
// consume from registers. Epilogue scratch stride 17 (bank-conflict-free).
__launch_bounds__(256, 4)
__global__ void k_off(const float* __restrict__ qf, const float* __restrict__ proto,
                      const float* __restrict__ wT, float* __restrict__ offp) {
    __shared__ __align__(16) float lds[8640];   // 80*108 = 34560 B
    int p = blockIdx.x;
    int kchunk = blockIdx.y;
    int cbase = kchunk * 80;
    int bi = p / (NQ * KW); int rem = p % (NQ * KW);
    int q = rem / KW; int k = rem % KW;
    const float* src = (cbase < C)
        ? qf + ((bi * NQ + q) * C + cbase) * HW
        : proto + ((bi * KW + k) * C + (cbase - C)) * HW;
    int tid = threadIdx.x;

    for (int i = tid; i < 8640; i += 256) lds[i] = 0.f;
    __syncthreads();
    for (int i = tid; i < 80 * 25; i += 256) {
        int cc = i / 25, pos = i % 25;
        lds[cc * 108 + (pos / 5 + 2) * 12 + (pos % 5 + 2)] = src[i];
    }
    __syncthreads();

    int kslice = tid / 15, tile = tid % 15;
    int sy = tile / 3, og8 = (tile % 3) * 8;
    float acc[5][6];
    #pragma unroll
    for (int i = 0; i < 5; ++i)
        #pragma unroll
        for (int j = 0; j < 6; ++j) acc[i][j] = 0.f;

    if (tid < 240) {
        for (int cp = 0; cp < 5; ++cp) {
            int cc = kslice * 5 + cp;
            const float* ibase = &lds[cc * 108];
            const float* wrow = wT + ((size_t)(cbase + cc) * 25) * 24 + og8;
            #pragma unroll
            for (int ky = 0; ky < 5; ++ky) {
                int r = sy + ky;
                float4 ra = *(const float4*)(ibase + r * 12);
                float4 rb = *(const float4*)(ibase + r * 12 + 4);
                float r8 = ibase[r * 12 + 8];
                float row[9] = {ra.x, ra.y, ra.z, ra.w, rb.x, rb.y, rb.z, rb.w, r8};
                #pragma unroll
                for (int kx = 0; kx < 5; ++kx) {
                    const float* wp = wrow + (ky * 5 + kx) * 24;
                    float wv[6];
                    #pragma unroll
                    for (int j2 = 0; j2 < 6; ++j2) wv[j2] = wp[j2];
                    #pragma unroll
                    for (int i2 = 0; i2 < 5; ++i2)
                        #pragma unroll
                        for (int j2 = 0; j2 < 6; ++j2)
                            acc[i2][j2] = fmaf(row[kx + i2], wv[j2], acc[i2][j2]);
                }
            }
        }
    }
    __syncthreads();
    // scratch: [450 outputs][17] (stride 17 => conflict-free)
    if (tid < 240) {
        #pragma unroll
        for (int i = 0; i < 5; ++i)
            #pragma unroll
            for (int j = 0; j < 6; ++j)
                lds[(tile * 30 + i * 6 + j) * 17 + kslice] = acc[i][j];
    }
    __syncthreads();
    float* dst = offp + ((size_t)p * 16 + kchunk) * 450;
    for (int oi = tid; oi < 450; oi += 256) {
        int tl = oi / 30, r2 = oi % 30, i = r2 / 6, j = r2 % 6;
        float s = 0.f;
        #pragma unroll
        for (int ks = 0; ks < 16; ++ks) s += lds[oi * 17 + ks];
        int o = (tl % 3) * 6 + j;
        dst[o * 25 + (tl / 3) * 5 + i] = s;
    }
}

// ---------------- reduce k_off partials ---------------------------------
__global__ void k_offred(const float* __restrict__ offp, float* __restrict__ offo) {
    int idx = blockIdx.x * 256 + threadIdx.x;
    if (idx >= P * 450) return;
    int p = idx / 450, e = idx % 450;
    float s = 0.f;
    #pragma unroll
    for (int kc = 0; kc < 16; ++kc) s += offp[((size_t)p * 16 + kc) * 450 + e];
    offo[idx] = s;
}

// ---------------- deformable 3x3 conv, C-split 8 ------------------------
__launch_bounds__(256)
__global__ void k_def(const float* __restrict__ proto, const float* __restrict__ offo,
                      const float* __restrict__ wdT, float* __restrict__ filtp) {
    __shared__ float flds[2000];     // [80 ch][25]
    __shared__ float wlds[8640];     // [(cc*9+kk)*12 + o]
    int p = blockIdx.x;
    int cs = blockIdx.y;
    int cbase = cs * 80;
    int bi = p / (NQ * KW); int rem = p % (NQ * KW);
    int k = rem % KW;
    const float* ftr = proto + ((bi * KW + k) * C + cbase) * HW;
    int tid = threadIdx.x;
    for (int i = tid; i < 2000; i += 256) flds[i] = ftr[i];
    for (int i = tid; i < 9 * 720; i += 256) {
        int kk = i / 720, r = i % 720;
        int cc = r / 9, o = r % 9;
        wlds[(cc * 9 + kk) * 12 + o] = wdT[(kk * C + cbase + cc) * 9 + o];
    }
    __syncthreads();

    float acc[9];
    #pragma unroll
    for (int o = 0; o < 9; ++o) acc[o] = 0.f;
    bool act = tid < 225;
    int hw = tid / 9, kk = tid % 9;
    if (act) {
        int h = hw / 5, w = hw % 5, ky = kk / 3, kx = kk % 3;
        float offY = offo[p * 450 + (kk * 2 + 0) * 25 + hw];
        float offX = offo[p * 450 + (kk * 2 + 1) * 25 + hw];
        float py = (float)(h + ky - 1) + offY;
        float px = (float)(w + kx - 1) + offX;
        float y0f = floorf(py), x0f = floorf(px);
        float ty = py - y0f, tx = px - x0f;
        int y0 = (int)y0f, x0 = (int)x0f;
        int y1 = y0 + 1, x1 = x0 + 1;
        bool vy0 = (y0 >= 0 && y0 < 5), vy1 = (y1 >= 0 && y1 < 5);
        bool vx0 = (x0 >= 0 && x0 < 5), vx1 = (x1 >= 0 && x1 < 5);
        int cy0 = min(max(y0, 0), 4), cy1 = min(max(y1, 0), 4);
        int cx0 = min(max(x0, 0), 4), cx1 = min(max(x1, 0), 4);
        int idx0 = cy0 * 5 + cx0, idx1 = cy0 * 5 + cx1;
        int idx2 = cy1 * 5 + cx0, idx3 = cy1 * 5 + cx1;
        float wb0 = (vy0 && vx0) ? (1.f - ty) * (1.f - tx) : 0.f;
        float wb1 = (vy0 && vx1) ? (1.f - ty) * tx : 0.f;
        float wb2 = (vy1 && vx0) ? ty * (1.f - tx) : 0.f;
        float wb3 = (vy1 && vx1) ? ty * tx : 0.f;
        for (int cc = 0; cc < 80; ++cc) {
            const float* base = &flds[cc * 25];
            float s = wb0 * base[idx0] + wb1 * base[idx1] + wb2 * base[idx2] + wb3 * base[idx3];
            const float* wr = &wlds[(cc * 9 + kk) * 12];
            #pragma unroll
            for (int o = 0; o < 9; ++o) acc[o] = fmaf(s, wr[o], acc[o]);
        }
    }
    __syncthreads();
    if (act) {
        #pragma unroll
        for (int o = 0; o < 9; ++o) flds[tid * 9 + o] = acc[o];
    }
    __syncthreads();
    if (tid < 225) {
        int hw2 = tid / 9, o2 = tid % 9;
        float s = 0.f;
        #pragma unroll
        for (int kk2 = 0; kk2 < 9; ++kk2) s += flds[(hw2 * 9 + kk2) * 9 + o2];
        filtp[((size_t)p * 8 + cs) * 225 + o2 * 25 + hw2] = s;
    }
}

// ---------------- reduce k_def partials + sigmoid -----------------------
__global__ void k_defred(const float* __restrict__ filtp, float* __restrict__ filt) {
    int idx = blockIdx.x * 256 + threadIdx.x;
    if (idx >= P * 225) return;
    int p = idx / 225, e = idx % 225;
    float s = 0.f;
    #pragma unroll
    for (int cs = 0; cs < 8; ++cs) s += filtp[((size_t)p * 8 + cs) * 225 + e];
    filt[idx] = 1.f / (1.f + expf(-s));
}

// ---------------- RK4 dynamic depthwise + class score -------------------
#define GSTEP(QA, KA)                                                       \
    {                                                                       \
        _Pragma("unroll")                                                   \
        for (int hw_ = 0; hw_ < 25; ++hw_) {                                \
            const int h_ = hw_ / 5, w_ = hw_ % 5;                           \
            float s_ = 0.f;                                                 \
            _Pragma("unroll")                                               \
            for (int kp_ = 0; kp_ < 9; ++kp_) {                             \
                const int y_ = h_ + kp_ / 3 - 1, x_ = w_ + kp_ % 3 - 1;     \
                if (y_ >= 0 && y_ < 5 && x_ >= 0 && x_ < 5)                 \
                    s_ = fmaf(QA[y_ * 5 + x_], fl[hw_ * 9 + kp_], s_);      \
            }                                                               \
            KA[hw_] = fmaxf(s_, 0.f);                                       \
        }                                                                   \
    }

__launch_bounds__(128)
__global__ void k_rk(const float* __restrict__ qf, const float* __restrict__ filt,
                     const float* __restrict__ cw, float* __restrict__ part) {
    __shared__ float fl[225];
    __shared__ float qlds[3200];     // 128 ch x 25
    __shared__ float wsum[2];
    int bid = blockIdx.x;
    int p = bid / 5, ch = bid % 5;
    int bi = p / (NQ * KW); int rem = p % (NQ * KW);
    int q = rem / KW; int k = rem % KW;
    int tid = threadIdx.x;
    int c = ch * 128 + tid;
    for (int i = tid; i < 225; i += 128) fl[i] = filt[p * 225 + i];
    const float* qbase = qf + ((bi * NQ + q) * C + ch * 128) * HW;
    for (int i = tid; i < 3200; i += 128) qlds[i] = qbase[i];
    __syncthreads();

    float F[25], K1[25], K2[25], K3[25], Q[25];
    #pragma unroll
    for (int i = 0; i < 25; ++i) F[i] = qlds[tid * 25 + i];

    GSTEP(F, K1);
    #pragma unroll
    for (int i = 0; i < 25; ++i) Q[i] = F[i] + K1[i] * (1.f / 3.f);
    GSTEP(Q, K2);
    #pragma unroll
    for (int i = 0; i < 25; ++i) Q[i] = F[i] + K2[i] - K1[i] * (1.f / 3.f);
    GSTEP(Q, K3);
    #pragma unroll
    for (int i = 0; i < 25; ++i) {
        Q[i] = F[i] + K1[i] - K2[i] + K3[i];
        K1[i] += 3.f * (K2[i] + K3[i]);
    }
    GSTEP(Q, K3);

    float S = 0.f;
    #pragma unroll
    for (int i = 0; i < 25; ++i) S += F[i] + (K1[i] + K3[i]) * 0.125f;

    float val = cw[(bi * KW + k) * C + c] * S;
    #pragma unroll
    for (int off = 32; off > 0; off >>= 1) val += __shfl_down(val, off, 64);
    if ((tid & 63) == 0) wsum[tid >> 6] = val;
    __syncthreads();
    if (tid == 0) part[p * 5 + ch] = wsum[0] + wsum[1];
}

// ---------------- final -------------------------------------------------
__global__ void k_fin(const float* __restrict__ part, float* __restrict__ out) {
    int i = blockIdx.x * 256 + threadIdx.x;
    if (i < P) {
        float s = 0.f;
        #pragma unroll
        for (int ch = 0; ch < 5; ++ch) s += part[i * 5 + ch];
        out[i] = s * (1.f / 49.f);
    }
}

extern "C" void kernel_launch(void* const* d_in, const int* in_sizes, int n_in,
                              void* d_out, int out_size, void* d_ws, size_t ws_size,
                              hipStream_t stream) {
    const float* sf    = (const float*)d_in[0];
    const float* qf    = (const float*)d_in[1];
    const float* st    = (const float*)d_in[2];
    const float* w_off = (const float*)d_in[4];
    const float* w_def = (const float*)d_in[5];
    float* out = (float*)d_out;
    float* ws  = (float*)d_ws;

    k_proto<<<(BB * KW * C * HW + 255) / 256, 256, 0, stream>>>(sf, st, ws + WS_PROTO);
    k_wt<<<(C2 * 25 * 24 + 255) / 256, 256, 0, stream>>>(w_off, ws + WS_WT);
    k_wd<<<(9 * C * 9 + 255) / 256, 256, 0, stream>>>(w_def, ws + WS_WDT);
    k_norm<<<1, 256, 0, stream>>>(ws + WS_PROTO, ws + WS_NORM);
    k_cw<<<(BB * KW * C + 255) / 256, 256, 0, stream>>>(ws + WS_PROTO, ws + WS_NORM, ws + WS_CW);
    k_off<<<dim3(P, 16), 256, 0, stream>>>(qf, ws + WS_PROTO, ws + WS_WT, ws + WS_OFFP);
    k_offred<<<(P * 450 + 255) / 256, 256, 0, stream>>>(ws + WS_OFFP, ws + WS_OFF);
    k_def<<<dim3(P, 8), 256, 0, stream>>>(ws + WS_PROTO, ws + WS_OFF, ws + WS_WDT, ws + WS_FILTP);
    k_defred<<<(P * 225 + 255) / 256, 256, 0, stream>>>(ws + WS_FILTP, ws + WS_FILT);
    k_rk<<<P * 5, 128, 0, stream>>>(qf, ws + WS_FILT, ws + WS_CW, ws + WS_PART);
    k_fin<<<1, 256, 0, stream>>>(ws + WS_PART, out);
}

// Round 4
// 111.637 us; speedup vs baseline: 6.0962x; 1.4532x over previous
//
#include <hip/hip_runtime.h>
#include <math.h>

// Problem constants
#define BB 2      // batch
#define NS 25     // support images
#define NQ 16     // queries
#define KW 5      // n_way
#define C  640
#define HW 25     // 5x5
#define C2 1280
#define P  160    // BB*NQ*KW

typedef unsigned short ushort_t;
typedef unsigned int uint_t;
typedef __attribute__((ext_vector_type(8))) short short8;

// Workspace layout (float offsets)
#define WS_PROTO   0          // 160000
#define WS_OFF     160000     // 72000
#define WS_FILT    232000     // 36000
#define WS_WDT     268000     // 51840
#define WS_NORM    319840     // 250
#define WS_CW      320090     // 6400
#define WS_PART    326490     // 800
#define WS_WMFH    327290     // 512000 floats (1.024M ushort)
#define WS_WMFL    839290     // 512000
#define WS_OFFP    1351290    // P*16*450 = 1152000
#define WS_FILTP   2503290    // 288000 -> end 2791290 (11.2 MB)

static __device__ inline ushort_t f2bf(float x) {
    uint_t u = __float_as_uint(x);
    uint_t r = (u + 0x7FFFu + ((u >> 16) & 1u)) >> 16;
    return (ushort_t)r;
}
static __device__ inline float bf2f(ushort_t b) {
    return __uint_as_float(((uint_t)b) << 16);
}

// ---------------- proto -------------------------------------------------
__global__ void k_proto(const float* __restrict__ sf, const float* __restrict__ st,
                        float* __restrict__ proto) {
    int idx = blockIdx.x * 256 + threadIdx.x;
    if (idx >= BB * KW * C * HW) return;
    int hw = idx % HW; int r = idx / HW;
    int c = r % C; r /= C;
    int k = r % KW; int bi = r / KW;
    float num = 0.f, den = 0.f;
    for (int n = 0; n < NS; ++n) {
        float w = st[(bi * NS + n) * KW + k];
        num += w * sf[((bi * NS + n) * C + c) * HW + hw];
        den += w;
    }
    proto[idx] = num / den;
}

// ---------------- norms -------------------------------------------------
__global__ void k_norm(const float* __restrict__ proto, float* __restrict__ norms) {
    int i = threadIdx.x;
    if (i >= BB * KW * HW) return;
    int hw = i % HW; int r = i / HW;
    int k = r % KW; int bi = r / KW;
    const float* pr = proto + ((bi * KW + k) * C) * HW + hw;
    float s = 0.f;
    for (int c = 0; c < C; ++c) { float v = pr[c * HW]; s += v * v; }
    norms[i] = fmaxf(sqrtf(s), 1e-12f);
}

// ---------------- cw ----------------------------------------------------
__global__ void k_cw(const float* __restrict__ proto, const float* __restrict__ norms,
                     float* __restrict__ cw) {
    int idx = blockIdx.x * 256 + threadIdx.x;
    if (idx >= BB * KW * C) return;
    int c = idx % C; int r = idx / C;
    int k = r % KW; int bi = r / KW;
    const float* pr = proto + ((bi * KW + k) * C + c) * HW;
    const float* nm = norms + (bi * KW + k) * HW;
    float s = 0.f;
    #pragma unroll
    for (int hw = 0; hw < HW; ++hw) s += pr[hw] / nm[hw];
    cw[idx] = s * (1.f / 25.f);
}

// ---------------- w_off -> MFMA A-fragments, hi/lo split ----------------
// layout: [kc(16)][t(25)][c16(5)][lane(64)][j(8)] bf16 bits.
// A-frag (32x32x16): row(o) = lane&31, k(c_local) = (lane>>5)*8 + j.
__global__ void k_wmf(const float* __restrict__ w_off, ushort_t* __restrict__ wh,
                      ushort_t* __restrict__ wl) {
    int idx = blockIdx.x * 256 + threadIdx.x;
    if (idx >= 16 * 25 * 5 * 64 * 8) return;
    int j = idx & 7;
    int lane = (idx >> 3) & 63;
    int c16 = (idx >> 9) % 5;
    int t = (idx / 2560) % 25;
    int kc = idx / 64000;
    int o = lane & 31;
    int c = kc * 80 + c16 * 16 + ((lane >> 5) << 3) + j;
    float w = (o < 18) ? w_off[(o * C2 + c) * 25 + t] : 0.f;
    ushort_t h = f2bf(w);
    wh[idx] = h;
    wl[idx] = f2bf(w - bf2f(h));
}

// ---------------- w_def transpose: wdT[(kk*C+c)*9 + o] ------------------
__global__ void k_wd(const float* __restrict__ w_def, float* __restrict__ wdT) {
    int idx = blockIdx.x * 256 + threadIdx.x;
    if (idx >= 9 * C * 9) return;
    int o = idx % 9; int r = idx / 9;
    int c = r % C; int kk = r / C;
    wdT[idx] = w_def[(o * C + c) * 9 + kk];
}

// ---------------- 5x5 offset conv via MFMA, K-split 16 ------------------
// grid (P, 16). Per block: 80 channels. Input staged in LDS as
// [81 padded pos][88 ch] bf16 (hi and lo planes). Per tap t, per 16-ch
// chunk: D[o(32),hw(32)] += A(W_t) x B(X_t) with v_mfma_f32_32x32x16_bf16.
// 3-pass hi/lo split: xh*wh + xh*wl + xl*wh (error ~1e-4).
// 4 waves split taps; LDS reduce over waves; f32 partials to offp.
__launch_bounds__(256, 3)
__global__ void k_off(const float* __restrict__ qf, const float* __restrict__ proto,
                      const ushort_t* __restrict__ wh, const ushort_t* __restrict__ wl,
                      float* __restrict__ offp) {
    __shared__ __align__(16) ushort_t sh[14256];   // Bhi[7128] | Blo[7128]; scr aliases
    ushort_t* Bhi = sh;
    ushort_t* Blo = sh + 7128;
    int p = blockIdx.x, kc = blockIdx.y;
    int cbase = kc * 80;
    int bi = p / (NQ * KW); int rem = p % (NQ * KW);
    int q = rem / KW; int k = rem % KW;
    const float* src = (cbase < C)
        ? qf + ((bi * NQ + q) * C + cbase) * HW
        : proto + ((bi * KW + k) * C + (cbase - C)) * HW;
    int tid = threadIdx.x;
    int lane = tid & 63, wv = tid >> 6;

    for (int i = tid; i < 3564; i += 256) { ((uint_t*)Bhi)[i] = 0u; ((uint_t*)Blo)[i] = 0u; }
    __syncthreads();
    for (int i = tid; i < 2000; i += 256) {
        int cc = i / 25, pp = i % 25;
        int pos = (pp / 5 + 2) * 9 + (pp % 5 + 2);
        float x = src[i];
        ushort_t h = f2bf(x);
        Bhi[pos * 88 + cc] = h;
        Blo[pos * 88 + cc] = f2bf(x - bf2f(h));
    }
    __syncthreads();

    // per-lane B base: col(hw) = lane&31 (hw>=25 lanes read pos 0 = zero pad)
    int hw = lane & 31;
    int by = (hw < 25) ? hw / 5 : 0;
    int bx = (hw < 25) ? hw % 5 : 0;
    int laneBase = (by * 9 + bx) * 88 + ((lane >> 5) << 3);

    typedef __attribute__((ext_vector_type(16))) float f32x16;
    f32x16 acc1, acc2, acc3;
    #pragma unroll
    for (int r = 0; r < 16; ++r) { acc1[r] = 0.f; acc2[r] = 0.f; acc3[r] = 0.f; }

    for (int t = wv; t < 25; t += 4) {
        int ty = t / 5, tx = t % 5;
        int tOff = laneBase + (ty * 9 + tx) * 88;
        const ushort_t* ah_p = wh + (((size_t)kc * 25 + t) * 5 * 64 + lane) * 8;
        const ushort_t* al_p = wl + (((size_t)kc * 25 + t) * 5 * 64 + lane) * 8;
        #pragma unroll
        for (int c16 = 0; c16 < 5; ++c16) {
            short8 bh = *(const short8*)&Bhi[tOff + c16 * 16];
            short8 bl = *(const short8*)&Blo[tOff + c16 * 16];
            short8 ah = *(const short8*)(ah_p + c16 * 512);
            short8 al = *(const short8*)(al_p + c16 * 512);
            acc1 = __builtin_amdgcn_mfma_f32_32x32x16_bf16(ah, bh, acc1, 0, 0, 0);
            acc2 = __builtin_amdgcn_mfma_f32_32x32x16_bf16(al, bh, acc2, 0, 0, 0);
            acc3 = __builtin_amdgcn_mfma_f32_32x32x16_bf16(ah, bl, acc3, 0, 0, 0);
        }
    }

    __syncthreads();          // all B reads done; alias scr over sh
    float* scr = (float*)sh;  // [16 regs][256 = wv*64+lane]
    #pragma unroll
    for (int r = 0; r < 16; ++r)
        scr[r * 256 + tid] = acc1[r] + acc2[r] + acc3[r];
    __syncthreads();

    // C/D layout (verified m74/m101): col = lane&31, row = (r&3)+8*(r>>2)+4*(lane>>5)
    float* dst = offp + ((size_t)p * 16 + kc) * 450;
    for (int i = tid; i < 450; i += 256) {
        int o = i / 25, hw2 = i % 25;
        int r = (o & 3) | ((o >> 3) << 2);
        int hi = (o >> 2) & 1;
        int ln = hw2 + hi * 32;
        float s = scr[r * 256 + ln] + scr[r * 256 + 64 + ln]
                + scr[r * 256 + 128 + ln] + scr[r * 256 + 192 + ln];
        dst[o * 25 + hw2] = s;
    }
}

// ---------------- reduce k_off partials ---------------------------------
__global__ void k_offred(const float* __restrict__ offp, float* __restrict__ offo) {
    int idx = blockIdx.x * 256 + threadIdx.x;
    if (idx >= P * 450) return;
    int p = idx / 450, e = idx % 450;
    float s = 0.f;
    #pragma unroll
    for (int kc = 0; kc < 16; ++kc) s += offp[((size_t)p * 16 + kc) * 450 + e];
    offo[idx] = s;
}

// ---------------- deformable 3x3 conv, C-split 8 ------------------------
__launch_bounds__(256)
__global__ void k_def(const float* __restrict__ proto, const float* __restrict__ offo,
                      const float* __restrict__ wdT, float* __restrict__ filtp) {
    __shared__ float flds[2000];     // [80 ch][25]
    __shared__ float wlds[8640];     // [(cc*9+kk)*12 + o]
    int p = blockIdx.x;
    int cs = blockIdx.y;
    int cbase = cs * 80;
    int bi = p / (NQ * KW); int rem = p % (NQ * KW);
    int k = rem % KW;
    const float* ftr = proto + ((bi * KW + k) * C + cbase) * HW;
    int tid = threadIdx.x;
    for (int i = tid; i < 2000; i += 256) flds[i] = ftr[i];
    for (int i = tid; i < 9 * 720; i += 256) {
        int kk = i / 720, r = i % 720;
        int cc = r / 9, o = r % 9;
        wlds[(cc * 9 + kk) * 12 + o] = wdT[(kk * C + cbase + cc) * 9 + o];
    }
    __syncthreads();

    float acc[9];
    #pragma unroll
    for (int o = 0; o < 9; ++o) acc[o] = 0.f;
    bool act = tid < 225;
    int hw = tid / 9, kk = tid % 9;
    if (act) {
        int h = hw / 5, w = hw % 5, ky = kk / 3, kx = kk % 3;
        float offY = offo[p * 450 + (kk * 2 + 0) * 25 + hw];
        float offX = offo[p * 450 + (kk * 2 + 1) * 25 + hw];
        float py = (float)(h + ky - 1) + offY;
        float px = (float)(w + kx - 1) + offX;
        float y0f = floorf(py), x0f = floorf(px);
        float ty = py - y0f, tx = px - x0f;
        int y0 = (int)y0f, x0 = (int)x0f;
        int y1 = y0 + 1, x1 = x0 + 1;
        bool vy0 = (y0 >= 0 && y0 < 5), vy1 = (y1 >= 0 && y1 < 5);
        bool vx0 = (x0 >= 0 && x0 < 5), vx1 = (x1 >= 0 && x1 < 5);
        int cy0 = min(max(y0, 0), 4), cy1 = min(max(y1, 0), 4);
        int cx0 = min(max(x0, 0), 4), cx1 = min(max(x1, 0), 4);
        int idx0 = cy0 * 5 + cx0, idx1 = cy0 * 5 + cx1;
        int idx2 = cy1 * 5 + cx0, idx3 = cy1 * 5 + cx1;
        float wb0 = (vy0 && vx0) ? (1.f - ty) * (1.f - tx) : 0.f;
        float wb1 = (vy0 && vx1) ? (1.f - ty) * tx : 0.f;
        float wb2 = (vy1 && vx0) ? ty * (1.f - tx) : 0.f;
        float wb3 = (vy1 && vx1) ? ty * tx : 0.f;
        for (int cc = 0; cc < 80; ++cc) {
            const float* base = &flds[cc * 25];
            float s = wb0 * base[idx0] + wb1 * base[idx1] + wb2 * base[idx2] + wb3 * base[idx3];
            const float* wr = &wlds[(cc * 9 + kk) * 12];
            #pragma unroll
            for (int o = 0; o < 9; ++o) acc[o] = fmaf(s, wr[o], acc[o]);
        }
    }
    __syncthreads();
    if (act) {
        #pragma unroll
        for (int o = 0; o < 9; ++o) flds[tid * 9 + o] = acc[o];
    }
    __syncthreads();
    if (tid < 225) {
        int hw2 = tid / 9, o2 = tid % 9;
        float s = 0.f;
        #pragma unroll
        for (int kk2 = 0; kk2 < 9; ++kk2) s += flds[(hw2 * 9 + kk2) * 9 + o2];
        filtp[((size_t)p * 8 + cs) * 225 + o2 * 25 + hw2] = s;
    }
}

// ---------------- reduce k_def partials + sigmoid -----------------------
__global__ void k_defred(const float* __restrict__ filtp, float* __restrict__ filt) {
    int idx = blockIdx.x * 256 + threadIdx.x;
    if (idx >= P * 225) return;
    int p = idx / 225, e = idx % 225;
    float s = 0.f;
    #pragma unroll
    for (int cs = 0; cs < 8; ++cs) s += filtp[((size_t)p * 8 + cs) * 225 + e];
    filt[idx] = 1.f / (1.f + expf(-s));
}

// ---------------- RK4 dynamic depthwise + class score -------------------
#define GSTEP(QA, KA)                                                       \
    {                                                                       \
        _Pragma("unroll")                                                   \
        for (int hw_ = 0; hw_ < 25; ++hw_) {                                \
            const int h_ = hw_ / 5, w_ = hw_ % 5;                           \
            float s_ = 0.f;                                                 \
            _Pragma("unroll")                                               \
            for (int kp_ = 0; kp_ < 9; ++kp_) {                             \
                const int y_ = h_ + kp_ / 3 - 1, x_ = w_ + kp_ % 3 - 1;     \
                if (y_ >= 0 && y_ < 5 && x_ >= 0 && x_ < 5)                 \
                    s_ = fmaf(QA[y_ * 5 + x_], fl[hw_ * 9 + kp_], s_);      \
            }                                                               \
            KA[hw_] = fmaxf(s_, 0.f);                                       \
        }                                                                   \
    }

__launch_bounds__(128)
__global__ void k_rk(const float* __restrict__ qf, const float* __restrict__ filt,
                     const float* __restrict__ cw, float* __restrict__ part) {
    __shared__ float fl[225];
    __shared__ float qlds[3200];     // 128 ch x 25
    __shared__ float wsum[2];
    int bid = blockIdx.x;
    int p = bid / 5, ch = bid % 5;
    int bi = p / (NQ * KW); int rem = p % (NQ * KW);
    int q = rem / KW; int k = rem % KW;
    int tid = threadIdx.x;
    int c = ch * 128 + tid;
    for (int i = tid; i < 225; i += 128) fl[i] = filt[p * 225 + i];
    const float* qbase = qf + ((bi * NQ + q) * C + ch * 128) * HW;
    for (int i = tid; i < 3200; i += 128) qlds[i] = qbase[i];
    __syncthreads();

    float F[25], K1[25], K2[25], K3[25], Q[25];
    #pragma unroll
    for (int i = 0; i < 25; ++i) F[i] = qlds[tid * 25 + i];

    GSTEP(F, K1);
    #pragma unroll
    for (int i = 0; i < 25; ++i) Q[i] = F[i] + K1[i] * (1.f / 3.f);
    GSTEP(Q, K2);
    #pragma unroll
    for (int i = 0; i < 25; ++i) Q[i] = F[i] + K2[i] - K1[i] * (1.f / 3.f);
    GSTEP(Q, K3);
    #pragma unroll
    for (int i = 0; i < 25; ++i) {
        Q[i] = F[i] + K1[i] - K2[i] + K3[i];
        K1[i] += 3.f * (K2[i] + K3[i]);
    }
    GSTEP(Q, K3);

    float S = 0.f;
    #pragma unroll
    for (int i = 0; i < 25; ++i) S += F[i] + (K1[i] + K3[i]) * 0.125f;

    float val = cw[(bi * KW + k) * C + c] * S;
    #pragma unroll
    for (int off = 32; off > 0; off >>= 1) val += __shfl_down(val, off, 64);
    if ((tid & 63) == 0) wsum[tid >> 6] = val;
    __syncthreads();
    if (tid == 0) part[p * 5 + ch] = wsum[0] + wsum[1];
}

// ---------------- final -------------------------------------------------
__global__ void k_fin(const float* __restrict__ part, float* __restrict__ out) {
    int i = blockIdx.x * 256 + threadIdx.x;
    if (i < P) {
        float s = 0.f;
        #pragma unroll
        for (int ch = 0; ch < 5; ++ch) s += part[i * 5 + ch];
        out[i] = s * (1.f / 49.f);
    }
}

extern "C" void kernel_launch(void* const* d_in, const int* in_sizes, int n_in,
                              void* d_out, int out_size, void* d_ws, size_t ws_size,
                              hipStream_t stream) {
    const float* sf    = (const float*)d_in[0];
    const float* qf    = (const float*)d_in[1];
    const float* st    = (const float*)d_in[2];
    const float* w_off = (const float*)d_in[4];
    const float* w_def = (const float*)d_in[5];
    float* out = (float*)d_out;
    float* ws  = (float*)d_ws;
    ushort_t* wmfh = (ushort_t*)(ws + WS_WMFH);
    ushort_t* wmfl = (ushort_t*)(ws + WS_WMFL);

    k_proto<<<(BB * KW * C * HW + 255) / 256, 256, 0, stream>>>(sf, st, ws + WS_PROTO);
    k_wmf<<<(16 * 25 * 5 * 64 * 8 + 255) / 256, 256, 0, stream>>>(w_off, wmfh, wmfl);
    k_wd<<<(9 * C * 9 + 255) / 256, 256, 0, stream>>>(w_def, ws + WS_WDT);
    k_norm<<<1, 256, 0, stream>>>(ws + WS_PROTO, ws + WS_NORM);
    k_cw<<<(BB * KW * C + 255) / 256, 256, 0, stream>>>(ws + WS_PROTO, ws + WS_NORM, ws + WS_CW);
    k_off<<<dim3(P, 16), 256, 0, stream>>>(qf, ws + WS_PROTO, wmfh, wmfl, ws + WS_OFFP);
    k_offred<<<(P * 450 + 255) / 256, 256, 0, stream>>>(ws + WS_OFFP, ws + WS_OFF);
    k_def<<<dim3(P, 8), 256, 0, stream>>>(ws + WS_PROTO, ws + WS_OFF, ws + WS_WDT, ws + WS_FILTP);
    k_defred<<<(P * 225 + 255) / 256, 256, 0, stream>>>(ws + WS_FILTP, ws + WS_FILT);
    k_rk<<<P * 5, 128, 0, stream>>>(qf, ws + WS_FILT, ws + WS_CW, ws + WS_PART);
    k_fin<<<1, 256, 0, stream>>>(ws + WS_PART, out);
}